// Round 1
// baseline (1892.397 us; speedup 1.0000x reference)
//
#include <hip/hip_runtime.h>

typedef unsigned short u16;
typedef unsigned int u32;

#define TT 2048
#define BB 4
#define EE 1024
#define HH 16
#define DD 64
#define LOG2E 1.4426950408889634f

typedef __bf16 bf16x8 __attribute__((ext_vector_type(8)));
typedef float f32x4 __attribute__((ext_vector_type(4)));

__device__ __forceinline__ f32x4 mfma16(bf16x8 a, bf16x8 b, f32x4 c) {
  return __builtin_amdgcn_mfma_f32_16x16x32_bf16(a, b, c, 0, 0, 0);
}

__device__ __forceinline__ u16 f2bf(float f) {
  u32 u = __float_as_uint(f);
  u += 0x7fffu + ((u >> 16) & 1u);   // RNE
  return (u16)(u >> 16);
}
__device__ __forceinline__ float bf2f(u16 u) {
  return __uint_as_float(((u32)u) << 16);
}

__device__ __forceinline__ void load_lds16(const void* g, void* l) {
  __builtin_amdgcn_global_load_lds((const __attribute__((address_space(1))) u32*)g,
                                   (__attribute__((address_space(3))) u32*)l, 16, 0, 0);
}

// ---------------- fp32 -> bf16 convert (x4 per thread) ----------------
__global__ __launch_bounds__(256) void cvt_kernel(const float* __restrict__ in,
                                                  u16* __restrict__ out, int n4) {
  int i = blockIdx.x * 256 + threadIdx.x;
  if (i >= n4) return;
  float4 v = ((const float4*)in)[i];
  u32 lo = (u32)f2bf(v.x) | ((u32)f2bf(v.y) << 16);
  u32 hi = (u32)f2bf(v.z) | ((u32)f2bf(v.w) << 16);
  ((uint2*)out)[i] = make_uint2(lo, hi);
}

// ---------------- C[M][N] = A[M][K] @ B[N][K]^T + bias ----------------
// 128x128 tile, BK=32, 256 threads (4 waves, each 64x64), m97-style staging.
template<bool BF16_OUT>
__global__ __launch_bounds__(256) void gemm_bt(const u16* __restrict__ A,
    const u16* __restrict__ B, const float* __restrict__ bias,
    void* __restrict__ Cp, int M, int N, int K)
{
  __shared__ u16 As[128 * 32];
  __shared__ u16 Bs[128 * 32];
  const int tid = threadIdx.x;
  const int m0 = blockIdx.y * 128;
  const int n0 = blockIdx.x * 128;
  const int w = tid >> 6, lane = tid & 63;
  const int quad = lane >> 4, l16 = lane & 15;
  const int wm = (w & 1) * 64, wn = (w >> 1) * 64;

  const f32x4 zero4 = {0.f, 0.f, 0.f, 0.f};
  f32x4 acc[4][4];
#pragma unroll
  for (int i = 0; i < 4; i++)
#pragma unroll
    for (int j = 0; j < 4; j++) acc[i][j] = zero4;

  for (int k0 = 0; k0 < K; k0 += 32) {
#pragma unroll
    for (int i = 0; i < 2; i++) {
      int c = i * 256 + tid;               // 512 chunks of 16B per tile
      int row = c >> 2, col = (c & 3) * 8;
      load_lds16(A + (size_t)(m0 + row) * K + k0 + col, &As[c * 8]);
      load_lds16(B + (size_t)(n0 + row) * K + k0 + col, &Bs[c * 8]);
    }
    __syncthreads();
    bf16x8 af[4], bfr[4];
#pragma unroll
    for (int i = 0; i < 4; i++)
      af[i] = *(const bf16x8*)&As[(wm + i * 16 + l16) * 32 + quad * 8];
#pragma unroll
    for (int j = 0; j < 4; j++)
      bfr[j] = *(const bf16x8*)&Bs[(wn + j * 16 + l16) * 32 + quad * 8];
#pragma unroll
    for (int i = 0; i < 4; i++)
#pragma unroll
      for (int j = 0; j < 4; j++)
        acc[i][j] = mfma16(af[i], bfr[j], acc[i][j]);
    __syncthreads();
  }
#pragma unroll
  for (int i = 0; i < 4; i++)
#pragma unroll
    for (int j = 0; j < 4; j++) {
      int col = n0 + wn + j * 16 + l16;
      float bv = bias[col];
#pragma unroll
      for (int r = 0; r < 4; r++) {
        int row = m0 + wm + i * 16 + quad * 4 + r;
        float v = acc[i][j][r] + bv;
        if (BF16_OUT) ((u16*)Cp)[(size_t)row * N + col] = f2bf(v);
        else          ((float*)Cp)[(size_t)row * N + col] = v;
      }
    }
}

// ---------------- RoPE on q,k; writes Q (scaled 0.125*log2e) and K as [BH][T][64] bf16 ----
__global__ __launch_bounds__(256) void rope_kernel(const u16* __restrict__ qkv,
    const float* __restrict__ pos, u16* __restrict__ Qg, u16* __restrict__ Kg)
{
  int u = blockIdx.x * 256 + threadIdx.x;      // 2,097,152 units
  int d0 = (u & 15) * 4;
  int h = (u >> 4) & 15;
  int m = u >> 8;                              // row of qkv = t*4 + b
  int t = m >> 2, b = m & 3;
  const u16* rowq = qkv + (size_t)m * 3072 + h * 64;
  uint2 qa = *(const uint2*)(rowq + d0);
  uint2 qb = *(const uint2*)(rowq + (d0 ^ 32));
  uint2 ka = *(const uint2*)(rowq + 1024 + d0);
  uint2 kb = *(const uint2*)(rowq + 1024 + (d0 ^ 32));
  float qv[4] = {bf2f((u16)(qa.x & 0xffff)), bf2f((u16)(qa.x >> 16)),
                 bf2f((u16)(qa.y & 0xffff)), bf2f((u16)(qa.y >> 16))};
  float qp[4] = {bf2f((u16)(qb.x & 0xffff)), bf2f((u16)(qb.x >> 16)),
                 bf2f((u16)(qb.y & 0xffff)), bf2f((u16)(qb.y >> 16))};
  float kv[4] = {bf2f((u16)(ka.x & 0xffff)), bf2f((u16)(ka.x >> 16)),
                 bf2f((u16)(ka.y & 0xffff)), bf2f((u16)(ka.y >> 16))};
  float kp[4] = {bf2f((u16)(kb.x & 0xffff)), bf2f((u16)(kb.x >> 16)),
                 bf2f((u16)(kb.y & 0xffff)), bf2f((u16)(kb.y >> 16))};
  float sgn = (d0 < 32) ? -1.f : 1.f;
  float qo[4], ko[4];
#pragma unroll
  for (int i = 0; i < 4; i++) {
    float a = pos[t * 64 + d0 + i];
    float sv, cv;
    sincosf(a, &sv, &cv);
    // fold scaling AND log2(e) into Q so attention exponentials are pure exp2
    qo[i] = (qv[i] * cv + sgn * qp[i] * sv) * 0.18033688f;  // 0.125 * log2(e)
    ko[i] = kv[i] * cv + sgn * kp[i] * sv;
  }
  size_t obase = ((size_t)(b * 16 + h) * TT + t) * 64 + d0;
  *(uint2*)(Qg + obase) = make_uint2((u32)f2bf(qo[0]) | ((u32)f2bf(qo[1]) << 16),
                                     (u32)f2bf(qo[2]) | ((u32)f2bf(qo[3]) << 16));
  *(uint2*)(Kg + obase) = make_uint2((u32)f2bf(ko[0]) | ((u32)f2bf(ko[1]) << 16),
                                     (u32)f2bf(ko[2]) | ((u32)f2bf(ko[3]) << 16));
}

// ---------------- V transpose: qkv v-part -> Vt [BH][64][T] bf16 ----------------
__global__ __launch_bounds__(256) void vtrans_kernel(const u16* __restrict__ qkv,
                                                     u16* __restrict__ Vt)
{
  __shared__ u16 Ls[64 * 64];                  // swizzled [t][d]
  int bh = blockIdx.y, b = bh >> 4, h = bh & 15;
  int t0 = blockIdx.x * 64;
  int tid = threadIdx.x;
#pragma unroll
  for (int i = 0; i < 2; i++) {
    int c = i * 256 + tid;                     // 512 chunks
    int r = c >> 3, ch = c & 7;
    int m = (t0 + r) * 4 + b;
    uint4 v = *(const uint4*)(qkv + (size_t)m * 3072 + 2048 + h * 64 + ch * 8);
    *(uint4*)&Ls[r * 64 + ((ch ^ (r & 7)) * 8)] = v;
  }
  __syncthreads();
#pragma unroll
  for (int i = 0; i < 2; i++) {
    int u = i * 256 + tid;
    int d = u >> 3, tc = u & 7;
    u32 pk[4];
#pragma unroll
    for (int p = 0; p < 4; p++) {
      int r0 = tc * 8 + p * 2, r1 = r0 + 1;
      u16 a = Ls[r0 * 64 + (((d >> 3) ^ (r0 & 7)) * 8) + (d & 7)];
      u16 bb = Ls[r1 * 64 + (((d >> 3) ^ (r1 & 7)) * 8) + (d & 7)];
      pk[p] = (u32)a | ((u32)bb << 16);
    }
    *(uint4*)(Vt + ((size_t)bh * 64 + d) * TT + t0 + tc * 8) =
        make_uint4(pk[0], pk[1], pk[2], pk[3]);
  }
}

// ---------------- fused causal attention ----------------
// grid (16 q-tiles, 64 bh). Two-phase: stats then P-write + PV.
// v2: async global_load_lds staging (pre-swizzled source, linear LDS dest),
//     double-buffered K/V with 1-tile prefetch, per-lane online softmax stats.
__global__ __launch_bounds__(256, 2) void attn_kernel(const u16* __restrict__ Qg,
    const u16* __restrict__ Kg, const u16* __restrict__ Vt,
    float* __restrict__ attn, u16* __restrict__ ctx)
{
  __shared__ u16 Ks[2][128 * 64];  // [s][d] swizzled, double-buffered
  __shared__ u16 Vs[2][64 * 128];  // [d][s] swizzled, double-buffered
  __shared__ u16 QPs[128 * 64];    // Q staging, later P-half buffer [t][s_half]

  const int bh = blockIdx.y;
  const int qt = (int)gridDim.x - 1 - (int)blockIdx.x;  // heavy tiles first
  const int b = bh >> 4, h = bh & 15;
  const int q0 = qt * 128;
  const int tid = threadIdx.x;
  const int w = tid >> 6, lane = tid & 63;
  const int quad = lane >> 4, l16 = lane & 15;
  const f32x4 zero4 = {0.f, 0.f, 0.f, 0.f};

  const u16* Kbase = Kg + (size_t)bh * TT * 64;
  const u16* Vbase = Vt + (size_t)bh * 64 * TT;

  // async stagers: LDS dest is linear in chunk index (global_load_lds
  // requirement); source address carries the XOR swizzle (involution).
  auto stageK = [&](int buf, int kt) {
    const u16* src = Kbase + (size_t)kt * 128 * 64;
#pragma unroll
    for (int i = 0; i < 4; i++) {
      int c = i * 256 + tid;
      int row = c >> 3, chl = c & 7;
      load_lds16(src + row * 64 + ((chl ^ (row & 7)) * 8), &Ks[buf][c * 8]);
    }
  };
  auto stageV = [&](int buf, int kt) {
    const u16* src = Vbase + kt * 128;
#pragma unroll
    for (int i = 0; i < 4; i++) {
      int c = i * 256 + tid;
      int d = c >> 4, chl = c & 15;
      load_lds16(src + (size_t)d * TT + ((chl ^ (d & 15)) * 8), &Vs[buf][c * 8]);
    }
  };

  { // stage Q tile (swizzled source -> linear LDS) + first K tile
    const u16* src = Qg + ((size_t)bh * TT + q0) * 64;
#pragma unroll
    for (int i = 0; i < 4; i++) {
      int c = i * 256 + tid;
      int row = c >> 3, chl = c & 7;
      load_lds16(src + row * 64 + ((chl ^ (row & 7)) * 8), &QPs[c * 8]);
    }
  }
  stageK(0, 0);
  __syncthreads();

  bf16x8 aq[2][2];
#pragma unroll
  for (int i = 0; i < 2; i++)
#pragma unroll
    for (int ks = 0; ks < 2; ks++) {
      int row = w * 32 + i * 16 + l16;
      int ch = (ks * 4 + quad) ^ (row & 7);
      aq[i][ks] = *(const bf16x8*)&QPs[row * 64 + ch * 8];
    }
  __syncthreads();   // all aq loaded before QPs is ever overwritten by P

  float mrow[8], lrow[8];
#pragma unroll
  for (int x = 0; x < 8; x++) { mrow[x] = -1e30f; lrow[x] = 0.f; }

  // ---- phase 1: softmax stats (per-lane online; merge across lanes once) ----
  int cur = 0;
  for (int kt = 0; kt <= qt; kt++) {
    if (kt < qt) stageK(cur ^ 1, kt + 1);   // async prefetch, drains at barrier
    f32x4 sacc[2][8];
#pragma unroll
    for (int i = 0; i < 2; i++)
#pragma unroll
      for (int j = 0; j < 8; j++) sacc[i][j] = zero4;
#pragma unroll
    for (int ks = 0; ks < 2; ks++)
#pragma unroll
      for (int j = 0; j < 8; j++) {
        int row = j * 16 + l16;
        int ch = (ks * 4 + quad) ^ (row & 7);
        bf16x8 bk = *(const bf16x8*)&Ks[cur][row * 64 + ch * 8];
        sacc[0][j] = mfma16(aq[0][ks], bk, sacc[0][j]);
        sacc[1][j] = mfma16(aq[1][ks], bk, sacc[1][j]);
      }
    if (kt == qt) {
#pragma unroll
      for (int i = 0; i < 2; i++)
#pragma unroll
        for (int j = 0; j < 8; j++) {
          int scol = j * 16 + l16;
#pragma unroll
          for (int r = 0; r < 4; r++) {
            int trow = w * 32 + i * 16 + quad * 4 + r;
            if (scol > trow) sacc[i][j][r] = -1e30f;
          }
        }
    }
    // per-lane online (m,l): no cross-lane ops inside the kt loop
#pragma unroll
    for (int i = 0; i < 2; i++)
#pragma unroll
      for (int r = 0; r < 4; r++) {
        int idx = i * 4 + r;
        float a0 = fmaxf(sacc[i][0][r], sacc[i][1][r]);
        float a1 = fmaxf(sacc[i][2][r], sacc[i][3][r]);
        float a2 = fmaxf(sacc[i][4][r], sacc[i][5][r]);
        float a3 = fmaxf(sacc[i][6][r], sacc[i][7][r]);
        float mx = fmaxf(fmaxf(a0, a1), fmaxf(a2, a3));
        float mnew = fmaxf(mrow[idx], mx);
        float s = 0.f;
#pragma unroll
        for (int j = 0; j < 8; j++) s += exp2f(sacc[i][j][r] - mnew);
        lrow[idx] = lrow[idx] * exp2f(mrow[idx] - mnew) + s;
        mrow[idx] = mnew;
      }
    __syncthreads();
    cur ^= 1;
  }

  // merge (m,l) across the 16 lanes sharing each accumulator row
  float inv_l[8];
#pragma unroll
  for (int idx = 0; idx < 8; idx++) {
    float m = mrow[idx], l = lrow[idx];
#pragma unroll
    for (int off = 1; off < 16; off <<= 1) {
      float mo = __shfl_xor(m, off);
      float lo = __shfl_xor(l, off);
      float mn = fmaxf(m, mo);
      l = l * exp2f(m - mn) + lo * exp2f(mo - mn);
      m = mn;
    }
    mrow[idx] = m;
    inv_l[idx] = 1.f / l;
  }

  f32x4 cacc[2][4];
#pragma unroll
  for (int i = 0; i < 2; i++)
#pragma unroll
    for (int j = 0; j < 4; j++) cacc[i][j] = zero4;

  // ---- phase 2: P write + PV (double-buffered K+V prefetch) ----
  stageK(cur, 0);
  stageV(cur, 0);
  __syncthreads();
  for (int kt = 0; kt <= qt; kt++) {
    if (kt < qt) { stageK(cur ^ 1, kt + 1); stageV(cur ^ 1, kt + 1); }
    f32x4 sacc[2][8];
#pragma unroll
    for (int i = 0; i < 2; i++)
#pragma unroll
      for (int j = 0; j < 8; j++) sacc[i][j] = zero4;
#pragma unroll
    for (int ks = 0; ks < 2; ks++)
#pragma unroll
      for (int j = 0; j < 8; j++) {
        int row = j * 16 + l16;
        int ch = (ks * 4 + quad) ^ (row & 7);
        bf16x8 bk = *(const bf16x8*)&Ks[cur][row * 64 + ch * 8];
        sacc[0][j] = mfma16(aq[0][ks], bk, sacc[0][j]);
        sacc[1][j] = mfma16(aq[1][ks], bk, sacc[1][j]);
      }
    if (kt == qt) {
#pragma unroll
      for (int i = 0; i < 2; i++)
#pragma unroll
        for (int j = 0; j < 8; j++) {
          int scol = j * 16 + l16;
#pragma unroll
          for (int r = 0; r < 4; r++) {
            int trow = w * 32 + i * 16 + quad * 4 + r;
            if (scol > trow) sacc[i][j][r] = -1e30f;
          }
        }
    }
    float* abase = attn + ((size_t)bh * TT + q0) * TT + kt * 128;
#pragma unroll
    for (int hf = 0; hf < 2; hf++) {
      // P for this 64-col half: write to global attn + LDS (A-layout round trip)
#pragma unroll
      for (int i = 0; i < 2; i++)
#pragma unroll
        for (int jl = 0; jl < 4; jl++) {
          int j = hf * 4 + jl;
#pragma unroll
          for (int r = 0; r < 4; r++) {
            int tr = w * 32 + i * 16 + quad * 4 + r;
            float p = exp2f(sacc[i][j][r] - mrow[i * 4 + r]) * inv_l[i * 4 + r];
            abase[(size_t)tr * TT + j * 16 + l16] = p;
            int sc = jl * 16 + l16;
            QPs[tr * 64 + (((sc >> 3) ^ (tr & 7)) * 8) + (sc & 7)] = f2bf(p);
          }
        }
      // PV over this half (wave-private P rows -> no barrier needed)
#pragma unroll
      for (int ks2 = 0; ks2 < 2; ks2++) {
        bf16x8 ap[2];
#pragma unroll
        for (int i = 0; i < 2; i++) {
          int row = w * 32 + i * 16 + l16;
          int ch = (ks2 * 4 + quad) ^ (row & 7);
          ap[i] = *(const bf16x8*)&QPs[row * 64 + ch * 8];
        }
#pragma unroll
        for (int j = 0; j < 4; j++) {
          int drow = j * 16 + l16;
          int ch = (hf * 8 + ks2 * 4 + quad) ^ (drow & 15);
          bf16x8 bv = *(const bf16x8*)&Vs[cur][drow * 128 + ch * 8];
          cacc[0][j] = mfma16(ap[0], bv, cacc[0][j]);
          cacc[1][j] = mfma16(ap[1], bv, cacc[1][j]);
        }
      }
    }
    __syncthreads();
    cur ^= 1;
  }

  // ctx out: [t][b][h*64+d] bf16 for the out-proj GEMM
#pragma unroll
  for (int i = 0; i < 2; i++)
#pragma unroll
    for (int j = 0; j < 4; j++)
#pragma unroll
      for (int r = 0; r < 4; r++) {
        int tr = q0 + w * 32 + i * 16 + quad * 4 + r;
        int d = j * 16 + l16;
        ctx[((size_t)tr * BB + b) * EE + h * 64 + d] = f2bf(cacc[i][j][r]);
      }

  // zero-fill the fully-masked future columns of this Q-tile
  int nz4 = (15 - qt) * 32;   // float4s per row
  if (nz4 > 0) {
    float4 z = make_float4(0.f, 0.f, 0.f, 0.f);
    float* base = attn + ((size_t)bh * TT + q0) * TT + (qt + 1) * 128;
    for (int r = 0; r < 128; r++)
      for (int c4 = tid; c4 < nz4; c4 += 256)
        *(float4*)(base + (size_t)r * TT + c4 * 4) = z;
  }
}

extern "C" void kernel_launch(void* const* d_in, const int* in_sizes, int n_in,
                              void* d_out, int out_size, void* d_ws, size_t ws_size,
                              hipStream_t stream) {
  (void)in_sizes; (void)n_in; (void)out_size; (void)ws_size;
  const float* input = (const float*)d_in[0];
  const float* pos   = (const float*)d_in[1];
  const float* in_w  = (const float*)d_in[2];
  const float* in_b  = (const float*)d_in[3];
  const float* out_w = (const float*)d_in[4];
  const float* out_b = (const float*)d_in[5];
  // d_in[6] (attn_mask) unused: causality computed from indices.

  float* out  = (float*)d_out;                       // [T,B,E] = 8,388,608 f32
  float* attn = out + (size_t)TT * BB * EE;          // [B,H,T,T] f32

  char* ws = (char*)d_ws;
  u16* inA = (u16*)ws;                               // input bf16, 16.78 MB
  u16* w1b = (u16*)(ws + 16777216);                  // 6.29 MB
  u16* w2b = (u16*)(ws + 23068672);                  // 2.10 MB
  u16* Qg  = (u16*)(ws + 25165824);                  // 16.78 MB
  u16* Kg  = (u16*)(ws + 41943040);                  // 16.78 MB
  u16* Vt  = (u16*)(ws + 58720256);                  // 16.78 MB (ends 75.5 MB)
  u16* ctx = inA;                                    // alias: inA dead after gemm1
  u16* qkv = (u16*)attn;                             // scratch inside attn region
                                                     // (consumed before attn_kernel)

  cvt_kernel<<<8192, 256, 0, stream>>>(input, inA, 2097152);
  cvt_kernel<<<3072, 256, 0, stream>>>(in_w, w1b, 786432);
  cvt_kernel<<<1024, 256, 0, stream>>>(out_w, w2b, 262144);
  gemm_bt<true><<<dim3(24, 64), 256, 0, stream>>>(inA, w1b, in_b, (void*)qkv,
                                                  8192, 3072, 1024);
  rope_kernel<<<8192, 256, 0, stream>>>(qkv, pos, Qg, Kg);
  vtrans_kernel<<<dim3(32, 64), 256, 0, stream>>>(qkv, Vt);
  attn_kernel<<<dim3(16, 64), 256, 0, stream>>>(Qg, Kg, Vt, attn, ctx);
  gemm_bt<false><<<dim3(8, 64), 256, 0, stream>>>(ctx, w2b, out_b, (void*)out,
                                                  8192, 1024, 1024);
}

// Round 2
// 1660.052 us; speedup vs baseline: 1.1400x; 1.1400x over previous
//
#include <hip/hip_runtime.h>

typedef unsigned short u16;
typedef unsigned int u32;

#define TT 2048
#define BB 4
#define EE 1024
#define HH 16
#define DD 64
#define LOG2E 1.4426950408889634f

typedef __bf16 bf16x8 __attribute__((ext_vector_type(8)));
typedef float f32x4 __attribute__((ext_vector_type(4)));

__device__ __forceinline__ f32x4 mfma16(bf16x8 a, bf16x8 b, f32x4 c) {
  return __builtin_amdgcn_mfma_f32_16x16x32_bf16(a, b, c, 0, 0, 0);
}

__device__ __forceinline__ u16 f2bf(float f) {
  u32 u = __float_as_uint(f);
  u += 0x7fffu + ((u >> 16) & 1u);   // RNE
  return (u16)(u >> 16);
}
__device__ __forceinline__ float bf2f(u16 u) {
  return __uint_as_float(((u32)u) << 16);
}

__device__ __forceinline__ void load_lds16(const void* g, void* l) {
  __builtin_amdgcn_global_load_lds((const __attribute__((address_space(1))) u32*)g,
                                   (__attribute__((address_space(3))) u32*)l, 16, 0, 0);
}

// ---------------- fp32 -> bf16 convert (x4 per thread) ----------------
__global__ __launch_bounds__(256) void cvt_kernel(const float* __restrict__ in,
                                                  u16* __restrict__ out, int n4) {
  int i = blockIdx.x * 256 + threadIdx.x;
  if (i >= n4) return;
  float4 v = ((const float4*)in)[i];
  u32 lo = (u32)f2bf(v.x) | ((u32)f2bf(v.y) << 16);
  u32 hi = (u32)f2bf(v.z) | ((u32)f2bf(v.w) << 16);
  ((uint2*)out)[i] = make_uint2(lo, hi);
}

// ---------------- C[M][N] = A[M][K] @ B[N][K]^T + bias ----------------
// 128x128 tile, BK=32, 256 threads (4 waves, each 64x64), m97-style staging.
template<bool BF16_OUT>
__global__ __launch_bounds__(256) void gemm_bt(const u16* __restrict__ A,
    const u16* __restrict__ B, const float* __restrict__ bias,
    void* __restrict__ Cp, int M, int N, int K)
{
  __shared__ u16 As[128 * 32];
  __shared__ u16 Bs[128 * 32];
  const int tid = threadIdx.x;
  const int m0 = blockIdx.y * 128;
  const int n0 = blockIdx.x * 128;
  const int w = tid >> 6, lane = tid & 63;
  const int quad = lane >> 4, l16 = lane & 15;
  const int wm = (w & 1) * 64, wn = (w >> 1) * 64;

  const f32x4 zero4 = {0.f, 0.f, 0.f, 0.f};
  f32x4 acc[4][4];
#pragma unroll
  for (int i = 0; i < 4; i++)
#pragma unroll
    for (int j = 0; j < 4; j++) acc[i][j] = zero4;

  for (int k0 = 0; k0 < K; k0 += 32) {
#pragma unroll
    for (int i = 0; i < 2; i++) {
      int c = i * 256 + tid;               // 512 chunks of 16B per tile
      int row = c >> 2, col = (c & 3) * 8;
      load_lds16(A + (size_t)(m0 + row) * K + k0 + col, &As[c * 8]);
      load_lds16(B + (size_t)(n0 + row) * K + k0 + col, &Bs[c * 8]);
    }
    __syncthreads();
    bf16x8 af[4], bfr[4];
#pragma unroll
    for (int i = 0; i < 4; i++)
      af[i] = *(const bf16x8*)&As[(wm + i * 16 + l16) * 32 + quad * 8];
#pragma unroll
    for (int j = 0; j < 4; j++)
      bfr[j] = *(const bf16x8*)&Bs[(wn + j * 16 + l16) * 32 + quad * 8];
#pragma unroll
    for (int i = 0; i < 4; i++)
#pragma unroll
      for (int j = 0; j < 4; j++)
        acc[i][j] = mfma16(af[i], bfr[j], acc[i][j]);
    __syncthreads();
  }
#pragma unroll
  for (int i = 0; i < 4; i++)
#pragma unroll
    for (int j = 0; j < 4; j++) {
      int col = n0 + wn + j * 16 + l16;
      float bv = bias[col];
#pragma unroll
      for (int r = 0; r < 4; r++) {
        int row = m0 + wm + i * 16 + quad * 4 + r;
        float v = acc[i][j][r] + bv;
        if (BF16_OUT) ((u16*)Cp)[(size_t)row * N + col] = f2bf(v);
        else          ((float*)Cp)[(size_t)row * N + col] = v;
      }
    }
}

// ---------------- RoPE on q,k; writes Q (scaled 0.125*log2e) and K as [BH][T][64] bf16 ----
__global__ __launch_bounds__(256) void rope_kernel(const u16* __restrict__ qkv,
    const float* __restrict__ pos, u16* __restrict__ Qg, u16* __restrict__ Kg)
{
  int u = blockIdx.x * 256 + threadIdx.x;      // 2,097,152 units
  int d0 = (u & 15) * 4;
  int h = (u >> 4) & 15;
  int m = u >> 8;                              // row of qkv = t*4 + b
  int t = m >> 2, b = m & 3;
  const u16* rowq = qkv + (size_t)m * 3072 + h * 64;
  uint2 qa = *(const uint2*)(rowq + d0);
  uint2 qb = *(const uint2*)(rowq + (d0 ^ 32));
  uint2 ka = *(const uint2*)(rowq + 1024 + d0);
  uint2 kb = *(const uint2*)(rowq + 1024 + (d0 ^ 32));
  float qv[4] = {bf2f((u16)(qa.x & 0xffff)), bf2f((u16)(qa.x >> 16)),
                 bf2f((u16)(qa.y & 0xffff)), bf2f((u16)(qa.y >> 16))};
  float qp[4] = {bf2f((u16)(qb.x & 0xffff)), bf2f((u16)(qb.x >> 16)),
                 bf2f((u16)(qb.y & 0xffff)), bf2f((u16)(qb.y >> 16))};
  float kv[4] = {bf2f((u16)(ka.x & 0xffff)), bf2f((u16)(ka.x >> 16)),
                 bf2f((u16)(ka.y & 0xffff)), bf2f((u16)(ka.y >> 16))};
  float kp[4] = {bf2f((u16)(kb.x & 0xffff)), bf2f((u16)(kb.x >> 16)),
                 bf2f((u16)(kb.y & 0xffff)), bf2f((u16)(kb.y >> 16))};
  float sgn = (d0 < 32) ? -1.f : 1.f;
  float qo[4], ko[4];
#pragma unroll
  for (int i = 0; i < 4; i++) {
    float a = pos[t * 64 + d0 + i];
    float sv, cv;
    sincosf(a, &sv, &cv);
    // fold scaling AND log2(e) into Q so attention exponentials are pure exp2
    qo[i] = (qv[i] * cv + sgn * qp[i] * sv) * 0.18033688f;  // 0.125 * log2(e)
    ko[i] = kv[i] * cv + sgn * kp[i] * sv;
  }
  size_t obase = ((size_t)(b * 16 + h) * TT + t) * 64 + d0;
  *(uint2*)(Qg + obase) = make_uint2((u32)f2bf(qo[0]) | ((u32)f2bf(qo[1]) << 16),
                                     (u32)f2bf(qo[2]) | ((u32)f2bf(qo[3]) << 16));
  *(uint2*)(Kg + obase) = make_uint2((u32)f2bf(ko[0]) | ((u32)f2bf(ko[1]) << 16),
                                     (u32)f2bf(ko[2]) | ((u32)f2bf(ko[3]) << 16));
}

// ---------------- V transpose: qkv v-part -> Vt [BH][64][T] bf16 ----------------
__global__ __launch_bounds__(256) void vtrans_kernel(const u16* __restrict__ qkv,
                                                     u16* __restrict__ Vt)
{
  __shared__ u16 Ls[64 * 64];                  // swizzled [t][d]
  int bh = blockIdx.y, b = bh >> 4, h = bh & 15;
  int t0 = blockIdx.x * 64;
  int tid = threadIdx.x;
#pragma unroll
  for (int i = 0; i < 2; i++) {
    int c = i * 256 + tid;                     // 512 chunks
    int r = c >> 3, ch = c & 7;
    int m = (t0 + r) * 4 + b;
    uint4 v = *(const uint4*)(qkv + (size_t)m * 3072 + 2048 + h * 64 + ch * 8);
    *(uint4*)&Ls[r * 64 + ((ch ^ (r & 7)) * 8)] = v;
  }
  __syncthreads();
#pragma unroll
  for (int i = 0; i < 2; i++) {
    int u = i * 256 + tid;
    int d = u >> 3, tc = u & 7;
    u32 pk[4];
#pragma unroll
    for (int p = 0; p < 4; p++) {
      int r0 = tc * 8 + p * 2, r1 = r0 + 1;
      u16 a = Ls[r0 * 64 + (((d >> 3) ^ (r0 & 7)) * 8) + (d & 7)];
      u16 bb = Ls[r1 * 64 + (((d >> 3) ^ (r1 & 7)) * 8) + (d & 7)];
      pk[p] = (u32)a | ((u32)bb << 16);
    }
    *(uint4*)(Vt + ((size_t)bh * 64 + d) * TT + t0 + tc * 8) =
        make_uint4(pk[0], pk[1], pk[2], pk[3]);
  }
}

// ---------------- fused causal attention ----------------
// grid (16 q-tiles, 64 bh). Two-phase: stats then P-write + PV.
// v3: 48 KB LDS pool (3 blocks/CU) with overlaid phase layouts:
//   phase 1: K double-buffer 2x(128x64)  [P/Q region idle]
//   phase 2: K 2x(64x64) + V 2x(64x64) + P (128x64)
// async global_load_lds staging (pre-swizzled source, linear LDS dest),
// 1-tile prefetch in both phases, per-lane online softmax stats.
__global__ __launch_bounds__(256, 3) void attn_kernel(const u16* __restrict__ Qg,
    const u16* __restrict__ Kg, const u16* __restrict__ Vt,
    float* __restrict__ attn, u16* __restrict__ ctx)
{
  __shared__ u16 sm[24576];        // 48 KB pool
  u16* QP = sm + 16384;            // Q staging, later P buffer [128][64]

  const int bh = blockIdx.y;
  const int qt = (int)gridDim.x - 1 - (int)blockIdx.x;  // heavy tiles first
  const int b = bh >> 4, h = bh & 15;
  const int q0 = qt * 128;
  const int tid = threadIdx.x;
  const int w = tid >> 6, lane = tid & 63;
  const int quad = lane >> 4, l16 = lane & 15;
  const f32x4 zero4 = {0.f, 0.f, 0.f, 0.f};

  const u16* Kbase = Kg + (size_t)bh * TT * 64;
  const u16* Vbase = Vt + (size_t)bh * 64 * TT;

  // async stagers: LDS dest linear in chunk index (global_load_lds
  // requirement); source address carries the XOR swizzle (involution).
  auto stageK128 = [&](int buf, int kt) {   // 128x64 tile -> sm + buf*8192
    const u16* src = Kbase + (size_t)kt * 128 * 64;
    u16* dst = sm + buf * 8192;
#pragma unroll
    for (int i = 0; i < 4; i++) {
      int c = i * 256 + tid;
      int row = c >> 3, chl = c & 7;
      load_lds16(src + row * 64 + ((chl ^ (row & 7)) * 8), dst + c * 8);
    }
  };
  auto stageK64 = [&](int buf, int kt) {    // 64x64 tile -> sm + buf*4096
    const u16* src = Kbase + (size_t)kt * 64 * 64;
    u16* dst = sm + buf * 4096;
#pragma unroll
    for (int i = 0; i < 2; i++) {
      int c = i * 256 + tid;
      int row = c >> 3, chl = c & 7;
      load_lds16(src + row * 64 + ((chl ^ (row & 7)) * 8), dst + c * 8);
    }
  };
  auto stageV64 = [&](int buf, int kt) {    // [64 d][64 s] -> sm + 8192 + buf*4096
    const u16* src = Vbase + kt * 64;
    u16* dst = sm + 8192 + buf * 4096;
#pragma unroll
    for (int i = 0; i < 2; i++) {
      int c = i * 256 + tid;
      int d = c >> 3, chl = c & 7;
      load_lds16(src + (size_t)d * TT + ((chl ^ (d & 7)) * 8), dst + c * 8);
    }
  };

  { // stage Q tile (swizzled source -> linear LDS) + first K tile
    const u16* src = Qg + ((size_t)bh * TT + q0) * 64;
#pragma unroll
    for (int i = 0; i < 4; i++) {
      int c = i * 256 + tid;
      int row = c >> 3, chl = c & 7;
      load_lds16(src + row * 64 + ((chl ^ (row & 7)) * 8), &QP[c * 8]);
    }
  }
  stageK128(0, 0);
  __syncthreads();

  // Q A-frags (wave-private rows; no extra barrier needed before P overwrites)
  bf16x8 aq[2][2];
#pragma unroll
  for (int i = 0; i < 2; i++)
#pragma unroll
    for (int ks = 0; ks < 2; ks++) {
      int row = w * 32 + i * 16 + l16;
      int ch = (ks * 4 + quad) ^ (row & 7);
      aq[i][ks] = *(const bf16x8*)&QP[row * 64 + ch * 8];
    }

  float mrow[8], lrow[8];
#pragma unroll
  for (int x = 0; x < 8; x++) { mrow[x] = -1e30f; lrow[x] = 0.f; }

  // ---- phase 1: softmax stats (128-wide K tiles, double-buffered) ----
  int cur = 0;
  for (int kt = 0; kt <= qt; kt++) {
    if (kt < qt) stageK128(cur ^ 1, kt + 1);   // async prefetch, drains at barrier
    const u16* Ks = sm + cur * 8192;
    f32x4 sacc[2][8];
#pragma unroll
    for (int i = 0; i < 2; i++)
#pragma unroll
      for (int j = 0; j < 8; j++) sacc[i][j] = zero4;
#pragma unroll
    for (int ks = 0; ks < 2; ks++)
#pragma unroll
      for (int j = 0; j < 8; j++) {
        int row = j * 16 + l16;
        int ch = (ks * 4 + quad) ^ (row & 7);
        bf16x8 bk = *(const bf16x8*)&Ks[row * 64 + ch * 8];
        sacc[0][j] = mfma16(aq[0][ks], bk, sacc[0][j]);
        sacc[1][j] = mfma16(aq[1][ks], bk, sacc[1][j]);
      }
    if (kt == qt) {
#pragma unroll
      for (int i = 0; i < 2; i++)
#pragma unroll
        for (int j = 0; j < 8; j++) {
          int scol = j * 16 + l16;
#pragma unroll
          for (int r = 0; r < 4; r++) {
            int trow = w * 32 + i * 16 + quad * 4 + r;
            if (scol > trow) sacc[i][j][r] = -1e30f;
          }
        }
    }
    // per-lane online (m,l): no cross-lane ops inside the kt loop
#pragma unroll
    for (int i = 0; i < 2; i++)
#pragma unroll
      for (int r = 0; r < 4; r++) {
        int idx = i * 4 + r;
        float a0 = fmaxf(sacc[i][0][r], sacc[i][1][r]);
        float a1 = fmaxf(sacc[i][2][r], sacc[i][3][r]);
        float a2 = fmaxf(sacc[i][4][r], sacc[i][5][r]);
        float a3 = fmaxf(sacc[i][6][r], sacc[i][7][r]);
        float mx = fmaxf(fmaxf(a0, a1), fmaxf(a2, a3));
        float mnew = fmaxf(mrow[idx], mx);
        float s = 0.f;
#pragma unroll
        for (int j = 0; j < 8; j++) s += exp2f(sacc[i][j][r] - mnew);
        lrow[idx] = lrow[idx] * exp2f(mrow[idx] - mnew) + s;
        mrow[idx] = mnew;
      }
    __syncthreads();
    cur ^= 1;
  }

  // merge (m,l) across the 16 lanes sharing each accumulator row
  float inv_l[8];
#pragma unroll
  for (int idx = 0; idx < 8; idx++) {
    float m = mrow[idx], l = lrow[idx];
#pragma unroll
    for (int off = 1; off < 16; off <<= 1) {
      float mo = __shfl_xor(m, off);
      float lo = __shfl_xor(l, off);
      float mn = fmaxf(m, mo);
      l = l * exp2f(m - mn) + lo * exp2f(mo - mn);
      m = mn;
    }
    mrow[idx] = m;
    inv_l[idx] = 1.f / l;
  }

  f32x4 cacc[2][4];
#pragma unroll
  for (int i = 0; i < 2; i++)
#pragma unroll
    for (int j = 0; j < 4; j++) cacc[i][j] = zero4;

  // ---- phase 2: P write + PV (64-wide KV tiles, K+V double-buffered) ----
  const int KT = 2 * (qt + 1);
  stageK64(0, 0);
  stageV64(0, 0);
  __syncthreads();
  cur = 0;
  for (int kt = 0; kt < KT; kt++) {
    if (kt < KT - 1) { stageK64(cur ^ 1, kt + 1); stageV64(cur ^ 1, kt + 1); }
    const u16* Ks = sm + cur * 4096;
    const u16* Vs = sm + 8192 + cur * 4096;
    f32x4 sacc[2][4];
#pragma unroll
    for (int i = 0; i < 2; i++)
#pragma unroll
      for (int j = 0; j < 4; j++) sacc[i][j] = zero4;
#pragma unroll
    for (int ks = 0; ks < 2; ks++)
#pragma unroll
      for (int j = 0; j < 4; j++) {
        int row = j * 16 + l16;
        int ch = (ks * 4 + quad) ^ (row & 7);
        bf16x8 bk = *(const bf16x8*)&Ks[row * 64 + ch * 8];
        sacc[0][j] = mfma16(aq[0][ks], bk, sacc[0][j]);
        sacc[1][j] = mfma16(aq[1][ks], bk, sacc[1][j]);
      }
    if (kt >= KT - 2) {                    // partial-mask tiles (diagonal)
      int off = kt * 64 - q0;              // 0 for kt=KT-2, 64 for kt=KT-1
#pragma unroll
      for (int i = 0; i < 2; i++)
#pragma unroll
        for (int j = 0; j < 4; j++) {
          int scol = j * 16 + l16;
#pragma unroll
          for (int r = 0; r < 4; r++) {
            int tl = w * 32 + i * 16 + quad * 4 + r;
            if (off + scol > tl) sacc[i][j][r] = -1e30f;
          }
        }
    }
    // P: write to global attn + LDS (A-layout round trip, wave-private rows)
    float* abase = attn + ((size_t)bh * TT + q0) * TT + kt * 64;
#pragma unroll
    for (int i = 0; i < 2; i++)
#pragma unroll
      for (int j = 0; j < 4; j++) {
#pragma unroll
        for (int r = 0; r < 4; r++) {
          int tr = w * 32 + i * 16 + quad * 4 + r;
          float p = exp2f(sacc[i][j][r] - mrow[i * 4 + r]) * inv_l[i * 4 + r];
          abase[(size_t)tr * TT + j * 16 + l16] = p;
          int sc = j * 16 + l16;
          QP[tr * 64 + (((sc >> 3) ^ (tr & 7)) * 8) + (sc & 7)] = f2bf(p);
        }
      }
    // PV (wave-private P rows -> no barrier needed)
#pragma unroll
    for (int ks2 = 0; ks2 < 2; ks2++) {
      bf16x8 ap[2];
#pragma unroll
      for (int i = 0; i < 2; i++) {
        int row = w * 32 + i * 16 + l16;
        int ch = (ks2 * 4 + quad) ^ (row & 7);
        ap[i] = *(const bf16x8*)&QP[row * 64 + ch * 8];
      }
#pragma unroll
      for (int j = 0; j < 4; j++) {
        int drow = j * 16 + l16;
        int ch = (ks2 * 4 + quad) ^ (drow & 7);
        bf16x8 bv = *(const bf16x8*)&Vs[drow * 64 + ch * 8];
        cacc[0][j] = mfma16(ap[0], bv, cacc[0][j]);
        cacc[1][j] = mfma16(ap[1], bv, cacc[1][j]);
      }
    }
    __syncthreads();
    cur ^= 1;
  }

  // ctx out: [t][b][h*64+d] bf16 for the out-proj GEMM
#pragma unroll
  for (int i = 0; i < 2; i++)
#pragma unroll
    for (int j = 0; j < 4; j++)
#pragma unroll
      for (int r = 0; r < 4; r++) {
        int tr = q0 + w * 32 + i * 16 + quad * 4 + r;
        int d = j * 16 + l16;
        ctx[((size_t)tr * BB + b) * EE + h * 64 + d] = f2bf(cacc[i][j][r]);
      }

  // zero-fill the fully-masked future columns of this Q-tile
  int nz4 = (15 - qt) * 32;   // float4s per row
  if (nz4 > 0) {
    float4 z = make_float4(0.f, 0.f, 0.f, 0.f);
    float* base = attn + ((size_t)bh * TT + q0) * TT + (qt + 1) * 128;
    for (int r = 0; r < 128; r++)
      for (int c4 = tid; c4 < nz4; c4 += 256)
        *(float4*)(base + (size_t)r * TT + c4 * 4) = z;
  }
}

extern "C" void kernel_launch(void* const* d_in, const int* in_sizes, int n_in,
                              void* d_out, int out_size, void* d_ws, size_t ws_size,
                              hipStream_t stream) {
  (void)in_sizes; (void)n_in; (void)out_size; (void)ws_size;
  const float* input = (const float*)d_in[0];
  const float* pos   = (const float*)d_in[1];
  const float* in_w  = (const float*)d_in[2];
  const float* in_b  = (const float*)d_in[3];
  const float* out_w = (const float*)d_in[4];
  const float* out_b = (const float*)d_in[5];
  // d_in[6] (attn_mask) unused: causality computed from indices.

  float* out  = (float*)d_out;                       // [T,B,E] = 8,388,608 f32
  float* attn = out + (size_t)TT * BB * EE;          // [B,H,T,T] f32

  char* ws = (char*)d_ws;
  u16* inA = (u16*)ws;                               // input bf16, 16.78 MB
  u16* w1b = (u16*)(ws + 16777216);                  // 6.29 MB
  u16* w2b = (u16*)(ws + 23068672);                  // 2.10 MB
  u16* Qg  = (u16*)(ws + 25165824);                  // 16.78 MB
  u16* Kg  = (u16*)(ws + 41943040);                  // 16.78 MB
  u16* Vt  = (u16*)(ws + 58720256);                  // 16.78 MB (ends 75.5 MB)
  u16* ctx = inA;                                    // alias: inA dead after gemm1
  u16* qkv = (u16*)attn;                             // scratch inside attn region
                                                     // (consumed before attn_kernel)

  cvt_kernel<<<8192, 256, 0, stream>>>(input, inA, 2097152);
  cvt_kernel<<<3072, 256, 0, stream>>>(in_w, w1b, 786432);
  cvt_kernel<<<1024, 256, 0, stream>>>(out_w, w2b, 262144);
  gemm_bt<true><<<dim3(24, 64), 256, 0, stream>>>(inA, w1b, in_b, (void*)qkv,
                                                  8192, 3072, 1024);
  rope_kernel<<<8192, 256, 0, stream>>>(qkv, pos, Qg, Kg);
  vtrans_kernel<<<dim3(32, 64), 256, 0, stream>>>(qkv, Vt);
  attn_kernel<<<dim3(16, 64), 256, 0, stream>>>(Qg, Kg, Vt, attn, ctx);
  gemm_bt<false><<<dim3(8, 64), 256, 0, stream>>>(ctx, w2b, out_b, (void*)out,
                                                  8192, 1024, 1024);
}

// Round 3
// 1385.247 us; speedup vs baseline: 1.3661x; 1.1984x over previous
//
#include <hip/hip_runtime.h>

typedef unsigned short u16;
typedef unsigned int u32;

#define TT 2048
#define BB 4
#define EE 1024
#define HH 16
#define DD 64
#define LOG2E 1.4426950408889634f

typedef __bf16 bf16x8 __attribute__((ext_vector_type(8)));
typedef float f32x4 __attribute__((ext_vector_type(4)));

__device__ __forceinline__ f32x4 mfma16(bf16x8 a, bf16x8 b, f32x4 c) {
  return __builtin_amdgcn_mfma_f32_16x16x32_bf16(a, b, c, 0, 0, 0);
}

__device__ __forceinline__ u16 f2bf(float f) {
  u32 u = __float_as_uint(f);
  u += 0x7fffu + ((u >> 16) & 1u);   // RNE
  return (u16)(u >> 16);
}
__device__ __forceinline__ float bf2f(u16 u) {
  return __uint_as_float(((u32)u) << 16);
}

__device__ __forceinline__ void load_lds16(const void* g, void* l) {
  __builtin_amdgcn_global_load_lds((const __attribute__((address_space(1))) u32*)g,
                                   (__attribute__((address_space(3))) u32*)l, 16, 0, 0);
}

// ---------------- fp32 -> bf16 convert (x4 per thread) ----------------
__global__ __launch_bounds__(256) void cvt_kernel(const float* __restrict__ in,
                                                  u16* __restrict__ out, int n4) {
  int i = blockIdx.x * 256 + threadIdx.x;
  if (i >= n4) return;
  float4 v = ((const float4*)in)[i];
  u32 lo = (u32)f2bf(v.x) | ((u32)f2bf(v.y) << 16);
  u32 hi = (u32)f2bf(v.z) | ((u32)f2bf(v.w) << 16);
  ((uint2*)out)[i] = make_uint2(lo, hi);
}

// ---------------- C[M][N] = A[M][K] @ B[N][K]^T + bias ----------------
// 128x128 tile, BK=32, 256 threads (4 waves, each 64x64), m97-style staging.
// XCD-aware bijective block swizzle (T1): nwg % 8 == 0 for all our launches.
template<bool BF16_OUT>
__global__ __launch_bounds__(256) void gemm_bt(const u16* __restrict__ A,
    const u16* __restrict__ B, const float* __restrict__ bias,
    void* __restrict__ Cp, int M, int N, int K)
{
  __shared__ u16 As[128 * 32];
  __shared__ u16 Bs[128 * 32];
  const int tid = threadIdx.x;
  const int nbx = gridDim.x;
  const int nwg = nbx * gridDim.y;
  int orig = blockIdx.y * nbx + blockIdx.x;
  int wg = (orig & 7) * (nwg >> 3) + (orig >> 3);  // bijective since nwg%8==0
  const int m0 = (wg / nbx) * 128;
  const int n0 = (wg % nbx) * 128;
  const int w = tid >> 6, lane = tid & 63;
  const int quad = lane >> 4, l16 = lane & 15;
  const int wm = (w & 1) * 64, wn = (w >> 1) * 64;

  const f32x4 zero4 = {0.f, 0.f, 0.f, 0.f};
  f32x4 acc[4][4];
#pragma unroll
  for (int i = 0; i < 4; i++)
#pragma unroll
    for (int j = 0; j < 4; j++) acc[i][j] = zero4;

  for (int k0 = 0; k0 < K; k0 += 32) {
#pragma unroll
    for (int i = 0; i < 2; i++) {
      int c = i * 256 + tid;               // 512 chunks of 16B per tile
      int row = c >> 2, col = (c & 3) * 8;
      load_lds16(A + (size_t)(m0 + row) * K + k0 + col, &As[c * 8]);
      load_lds16(B + (size_t)(n0 + row) * K + k0 + col, &Bs[c * 8]);
    }
    __syncthreads();
    bf16x8 af[4], bfr[4];
#pragma unroll
    for (int i = 0; i < 4; i++)
      af[i] = *(const bf16x8*)&As[(wm + i * 16 + l16) * 32 + quad * 8];
#pragma unroll
    for (int j = 0; j < 4; j++)
      bfr[j] = *(const bf16x8*)&Bs[(wn + j * 16 + l16) * 32 + quad * 8];
#pragma unroll
    for (int i = 0; i < 4; i++)
#pragma unroll
      for (int j = 0; j < 4; j++)
        acc[i][j] = mfma16(af[i], bfr[j], acc[i][j]);
    __syncthreads();
  }
#pragma unroll
  for (int i = 0; i < 4; i++)
#pragma unroll
    for (int j = 0; j < 4; j++) {
      int col = n0 + wn + j * 16 + l16;
      float bv = bias[col];
#pragma unroll
      for (int r = 0; r < 4; r++) {
        int row = m0 + wm + i * 16 + quad * 4 + r;
        float v = acc[i][j][r] + bv;
        if (BF16_OUT) ((u16*)Cp)[(size_t)row * N + col] = f2bf(v);
        else          ((float*)Cp)[(size_t)row * N + col] = v;
      }
    }
}

// ---------------- RoPE on q,k; writes Q (scaled 0.125*log2e) and K as [BH][T][64] bf16 ----
__global__ __launch_bounds__(256) void rope_kernel(const u16* __restrict__ qkv,
    const float* __restrict__ pos, u16* __restrict__ Qg, u16* __restrict__ Kg)
{
  int u = blockIdx.x * 256 + threadIdx.x;      // 2,097,152 units
  int d0 = (u & 15) * 4;
  int h = (u >> 4) & 15;
  int m = u >> 8;                              // row of qkv = t*4 + b
  int t = m >> 2, b = m & 3;
  const u16* rowq = qkv + (size_t)m * 3072 + h * 64;
  uint2 qa = *(const uint2*)(rowq + d0);
  uint2 qb = *(const uint2*)(rowq + (d0 ^ 32));
  uint2 ka = *(const uint2*)(rowq + 1024 + d0);
  uint2 kb = *(const uint2*)(rowq + 1024 + (d0 ^ 32));
  float qv[4] = {bf2f((u16)(qa.x & 0xffff)), bf2f((u16)(qa.x >> 16)),
                 bf2f((u16)(qa.y & 0xffff)), bf2f((u16)(qa.y >> 16))};
  float qp[4] = {bf2f((u16)(qb.x & 0xffff)), bf2f((u16)(qb.x >> 16)),
                 bf2f((u16)(qb.y & 0xffff)), bf2f((u16)(qb.y >> 16))};
  float kv[4] = {bf2f((u16)(ka.x & 0xffff)), bf2f((u16)(ka.x >> 16)),
                 bf2f((u16)(ka.y & 0xffff)), bf2f((u16)(ka.y >> 16))};
  float kp[4] = {bf2f((u16)(kb.x & 0xffff)), bf2f((u16)(kb.x >> 16)),
                 bf2f((u16)(kb.y & 0xffff)), bf2f((u16)(kb.y >> 16))};
  float sgn = (d0 < 32) ? -1.f : 1.f;
  float qo[4], ko[4];
#pragma unroll
  for (int i = 0; i < 4; i++) {
    float a = pos[t * 64 + d0 + i];
    float sv, cv;
    sincosf(a, &sv, &cv);
    // fold scaling AND log2(e) into Q so attention exponentials are pure exp2
    qo[i] = (qv[i] * cv + sgn * qp[i] * sv) * 0.18033688f;  // 0.125 * log2(e)
    ko[i] = kv[i] * cv + sgn * kp[i] * sv;
  }
  size_t obase = ((size_t)(b * 16 + h) * TT + t) * 64 + d0;
  *(uint2*)(Qg + obase) = make_uint2((u32)f2bf(qo[0]) | ((u32)f2bf(qo[1]) << 16),
                                     (u32)f2bf(qo[2]) | ((u32)f2bf(qo[3]) << 16));
  *(uint2*)(Kg + obase) = make_uint2((u32)f2bf(ko[0]) | ((u32)f2bf(ko[1]) << 16),
                                     (u32)f2bf(ko[2]) | ((u32)f2bf(ko[3]) << 16));
}

// ---------------- V transpose: qkv v-part -> Vt [BH][64][T] bf16 ----------------
__global__ __launch_bounds__(256) void vtrans_kernel(const u16* __restrict__ qkv,
                                                     u16* __restrict__ Vt)
{
  __shared__ u16 Ls[64 * 64];                  // swizzled [t][d]
  int bh = blockIdx.y, b = bh >> 4, h = bh & 15;
  int t0 = blockIdx.x * 64;
  int tid = threadIdx.x;
#pragma unroll
  for (int i = 0; i < 2; i++) {
    int c = i * 256 + tid;                     // 512 chunks
    int r = c >> 3, ch = c & 7;
    int m = (t0 + r) * 4 + b;
    uint4 v = *(const uint4*)(qkv + (size_t)m * 3072 + 2048 + h * 64 + ch * 8);
    *(uint4*)&Ls[r * 64 + ((ch ^ (r & 7)) * 8)] = v;
  }
  __syncthreads();
#pragma unroll
  for (int i = 0; i < 2; i++) {
    int u = i * 256 + tid;
    int d = u >> 3, tc = u & 7;
    u32 pk[4];
#pragma unroll
    for (int p = 0; p < 4; p++) {
      int r0 = tc * 8 + p * 2, r1 = r0 + 1;
      u16 a = Ls[r0 * 64 + (((d >> 3) ^ (r0 & 7)) * 8) + (d & 7)];
      u16 bb = Ls[r1 * 64 + (((d >> 3) ^ (r1 & 7)) * 8) + (d & 7)];
      pk[p] = (u32)a | ((u32)bb << 16);
    }
    *(uint4*)(Vt + ((size_t)bh * 64 + d) * TT + t0 + tc * 8) =
        make_uint4(pk[0], pk[1], pk[2], pk[3]);
  }
}

// ---------------- fused causal attention ----------------
// v4: QBLK=64 rows/block, grid (32 q-tiles, 64 bh). 40 KB LDS pool -> 4 blocks/CU.
//   phase 1: K double-buffer 2x(128x64) = 32 KB   [P/Q region idle]
//   phase 2: K 2x(64x64) + V 2x(64x64) = 32 KB + P (64x64) 8 KB
// async global_load_lds staging (pre-swizzled source, linear LDS dest),
// 1-tile prefetch in both phases, per-lane online softmax stats.
__global__ __launch_bounds__(256, 4) void attn_kernel(const u16* __restrict__ Qg,
    const u16* __restrict__ Kg, const u16* __restrict__ Vt,
    float* __restrict__ attn, u16* __restrict__ ctx)
{
  __shared__ u16 sm[20480];        // 40 KB pool
  u16* QP = sm + 16384;            // Q staging / P buffer [64][64]

  const int bh = blockIdx.y;
  const int qt = (int)gridDim.x - 1 - (int)blockIdx.x;  // 0..31, heavy tiles first
  const int b = bh >> 4, h = bh & 15;
  const int q0 = qt * 64;
  const int tid = threadIdx.x;
  const int w = tid >> 6, lane = tid & 63;
  const int quad = lane >> 4, l16 = lane & 15;
  const f32x4 zero4 = {0.f, 0.f, 0.f, 0.f};

  const u16* Kbase = Kg + (size_t)bh * TT * 64;
  const u16* Vbase = Vt + (size_t)bh * 64 * TT;

  // async stagers: LDS dest linear in chunk index (global_load_lds
  // requirement); source address carries the XOR swizzle (involution).
  auto stageK128 = [&](int buf, int kt2) {  // 128x64 tile -> sm + buf*8192
    const u16* src = Kbase + (size_t)kt2 * 128 * 64;
    u16* dst = sm + buf * 8192;
#pragma unroll
    for (int i = 0; i < 4; i++) {
      int c = i * 256 + tid;
      int row = c >> 3, chl = c & 7;
      load_lds16(src + row * 64 + ((chl ^ (row & 7)) * 8), dst + c * 8);
    }
  };
  auto stageK64 = [&](int buf, int kt) {    // 64x64 tile -> sm + buf*4096
    const u16* src = Kbase + (size_t)kt * 64 * 64;
    u16* dst = sm + buf * 4096;
#pragma unroll
    for (int i = 0; i < 2; i++) {
      int c = i * 256 + tid;
      int row = c >> 3, chl = c & 7;
      load_lds16(src + row * 64 + ((chl ^ (row & 7)) * 8), dst + c * 8);
    }
  };
  auto stageV64 = [&](int buf, int kt) {    // [64 d][64 s] -> sm + 8192 + buf*4096
    const u16* src = Vbase + kt * 64;
    u16* dst = sm + 8192 + buf * 4096;
#pragma unroll
    for (int i = 0; i < 2; i++) {
      int c = i * 256 + tid;
      int d = c >> 3, chl = c & 7;
      load_lds16(src + (size_t)d * TT + ((chl ^ (d & 7)) * 8), dst + c * 8);
    }
  };

  { // stage Q tile (64 rows, swizzled source -> linear LDS) + first K128 tile
    const u16* src = Qg + ((size_t)bh * TT + q0) * 64;
#pragma unroll
    for (int i = 0; i < 2; i++) {
      int c = i * 256 + tid;
      int row = c >> 3, chl = c & 7;
      load_lds16(src + row * 64 + ((chl ^ (row & 7)) * 8), &QP[c * 8]);
    }
  }
  stageK128(0, 0);
  __syncthreads();

  // Q A-frag: wave w owns rows w*16..w*16+15 (wave-private; P overwrite safe)
  bf16x8 aq[2];
#pragma unroll
  for (int ks = 0; ks < 2; ks++) {
    int row = w * 16 + l16;
    int ch = (ks * 4 + quad) ^ (row & 7);
    aq[ks] = *(const bf16x8*)&QP[row * 64 + ch * 8];
  }

  float mrow[4], lrow[4];
#pragma unroll
  for (int x = 0; x < 4; x++) { mrow[x] = -1e30f; lrow[x] = 0.f; }

  // ---- phase 1: softmax stats (128-wide K tiles, double-buffered) ----
  const int nk1 = (qt >> 1) + 1;
  int cur = 0;
  for (int kt = 0; kt < nk1; kt++) {
    if (kt < nk1 - 1) stageK128(cur ^ 1, kt + 1);  // async prefetch
    const u16* Ks = sm + cur * 8192;
    f32x4 sacc[8];
#pragma unroll
    for (int j = 0; j < 8; j++) sacc[j] = zero4;
#pragma unroll
    for (int ks = 0; ks < 2; ks++)
#pragma unroll
      for (int j = 0; j < 8; j++) {
        int row = j * 16 + l16;
        int ch = (ks * 4 + quad) ^ (row & 7);
        bf16x8 bk = *(const bf16x8*)&Ks[row * 64 + ch * 8];
        sacc[j] = mfma16(aq[ks], bk, sacc[j]);
      }
    if (kt == nk1 - 1) {                 // only the last tile can cross the diagonal
#pragma unroll
      for (int j = 0; j < 8; j++) {
        int scol = kt * 128 + j * 16 + l16;
#pragma unroll
        for (int r = 0; r < 4; r++) {
          int trow = q0 + w * 16 + quad * 4 + r;
          if (scol > trow) sacc[j][r] = -1e30f;
        }
      }
    }
    // per-lane online (m,l): no cross-lane ops inside the kt loop
#pragma unroll
    for (int r = 0; r < 4; r++) {
      float a0 = fmaxf(sacc[0][r], sacc[1][r]);
      float a1 = fmaxf(sacc[2][r], sacc[3][r]);
      float a2 = fmaxf(sacc[4][r], sacc[5][r]);
      float a3 = fmaxf(sacc[6][r], sacc[7][r]);
      float mx = fmaxf(fmaxf(a0, a1), fmaxf(a2, a3));
      float mnew = fmaxf(mrow[r], mx);
      float s = 0.f;
#pragma unroll
      for (int j = 0; j < 8; j++) s += exp2f(sacc[j][r] - mnew);
      lrow[r] = lrow[r] * exp2f(mrow[r] - mnew) + s;
      mrow[r] = mnew;
    }
    __syncthreads();
    cur ^= 1;
  }

  // merge (m,l) across the 16 lanes sharing each accumulator row
  float inv_l[4];
#pragma unroll
  for (int idx = 0; idx < 4; idx++) {
    float m = mrow[idx], l = lrow[idx];
#pragma unroll
    for (int off = 1; off < 16; off <<= 1) {
      float mo = __shfl_xor(m, off);
      float lo = __shfl_xor(l, off);
      float mn = fmaxf(m, mo);
      l = l * exp2f(m - mn) + lo * exp2f(mo - mn);
      m = mn;
    }
    mrow[idx] = m;
    inv_l[idx] = 1.f / l;
  }

  f32x4 cacc[4];
#pragma unroll
  for (int j = 0; j < 4; j++) cacc[j] = zero4;

  // ---- phase 2: P write + PV (64-wide KV tiles, K+V double-buffered) ----
  const int nk2 = qt + 1;
  stageK64(0, 0);
  stageV64(0, 0);
  __syncthreads();
  cur = 0;
  for (int kt = 0; kt < nk2; kt++) {
    if (kt < nk2 - 1) { stageK64(cur ^ 1, kt + 1); stageV64(cur ^ 1, kt + 1); }
    const u16* Ks = sm + cur * 4096;
    const u16* Vs = sm + 8192 + cur * 4096;
    f32x4 sacc[4];
#pragma unroll
    for (int j = 0; j < 4; j++) sacc[j] = zero4;
#pragma unroll
    for (int ks = 0; ks < 2; ks++)
#pragma unroll
      for (int j = 0; j < 4; j++) {
        int row = j * 16 + l16;
        int ch = (ks * 4 + quad) ^ (row & 7);
        bf16x8 bk = *(const bf16x8*)&Ks[row * 64 + ch * 8];
        sacc[j] = mfma16(aq[ks], bk, sacc[j]);
      }
    if (kt == nk2 - 1) {                 // diagonal tile (s0 == q0)
#pragma unroll
      for (int j = 0; j < 4; j++) {
        int scol = j * 16 + l16;
#pragma unroll
        for (int r = 0; r < 4; r++) {
          int tl = w * 16 + quad * 4 + r;
          if (scol > tl) sacc[j][r] = -1e30f;
        }
      }
    }
    // P: write to global attn + LDS (A-layout round trip, wave-private rows)
    float* abase = attn + ((size_t)bh * TT + q0) * TT + kt * 64;
#pragma unroll
    for (int j = 0; j < 4; j++) {
#pragma unroll
      for (int r = 0; r < 4; r++) {
        int tr = w * 16 + quad * 4 + r;
        float p = exp2f(sacc[j][r] - mrow[r]) * inv_l[r];
        abase[(size_t)tr * TT + j * 16 + l16] = p;
        int sc = j * 16 + l16;
        QP[tr * 64 + (((sc >> 3) ^ (tr & 7)) * 8) + (sc & 7)] = f2bf(p);
      }
    }
    // PV (wave-private P rows -> no barrier needed)
#pragma unroll
    for (int ks2 = 0; ks2 < 2; ks2++) {
      bf16x8 ap;
      {
        int row = w * 16 + l16;
        int ch = (ks2 * 4 + quad) ^ (row & 7);
        ap = *(const bf16x8*)&QP[row * 64 + ch * 8];
      }
#pragma unroll
      for (int j = 0; j < 4; j++) {
        int drow = j * 16 + l16;
        int ch = (ks2 * 4 + quad) ^ (drow & 7);
        bf16x8 bv = *(const bf16x8*)&Vs[drow * 64 + ch * 8];
        cacc[j] = mfma16(ap, bv, cacc[j]);
      }
    }
    __syncthreads();
    cur ^= 1;
  }

  // ctx out: [t][b][h*64+d] bf16 for the out-proj GEMM
#pragma unroll
  for (int j = 0; j < 4; j++)
#pragma unroll
    for (int r = 0; r < 4; r++) {
      int tr = q0 + w * 16 + quad * 4 + r;
      int d = j * 16 + l16;
      ctx[((size_t)tr * BB + b) * EE + h * 64 + d] = f2bf(cacc[j][r]);
    }

  // zero-fill the fully-masked future columns of this Q-tile
  int nz4 = (31 - qt) * 16;   // float4s per row
  if (nz4 > 0) {
    float4 z = make_float4(0.f, 0.f, 0.f, 0.f);
    float* base = attn + ((size_t)bh * TT + q0) * TT + (qt + 1) * 64;
    for (int r = 0; r < 64; r++)
      for (int c4 = tid; c4 < nz4; c4 += 256)
        *(float4*)(base + (size_t)r * TT + c4 * 4) = z;
  }
}

extern "C" void kernel_launch(void* const* d_in, const int* in_sizes, int n_in,
                              void* d_out, int out_size, void* d_ws, size_t ws_size,
                              hipStream_t stream) {
  (void)in_sizes; (void)n_in; (void)out_size; (void)ws_size;
  const float* input = (const float*)d_in[0];
  const float* pos   = (const float*)d_in[1];
  const float* in_w  = (const float*)d_in[2];
  const float* in_b  = (const float*)d_in[3];
  const float* out_w = (const float*)d_in[4];
  const float* out_b = (const float*)d_in[5];
  // d_in[6] (attn_mask) unused: causality computed from indices.

  float* out  = (float*)d_out;                       // [T,B,E] = 8,388,608 f32
  float* attn = out + (size_t)TT * BB * EE;          // [B,H,T,T] f32

  char* ws = (char*)d_ws;
  u16* inA = (u16*)ws;                               // input bf16, 16.78 MB
  u16* w1b = (u16*)(ws + 16777216);                  // 6.29 MB
  u16* w2b = (u16*)(ws + 23068672);                  // 2.10 MB
  u16* Qg  = (u16*)(ws + 25165824);                  // 16.78 MB
  u16* Kg  = (u16*)(ws + 41943040);                  // 16.78 MB
  u16* Vt  = (u16*)(ws + 58720256);                  // 16.78 MB (ends 75.5 MB)
  u16* ctx = inA;                                    // alias: inA dead after gemm1
  u16* qkv = (u16*)attn;                             // scratch inside attn region
                                                     // (consumed before attn_kernel)

  cvt_kernel<<<8192, 256, 0, stream>>>(input, inA, 2097152);
  cvt_kernel<<<3072, 256, 0, stream>>>(in_w, w1b, 786432);
  cvt_kernel<<<1024, 256, 0, stream>>>(out_w, w2b, 262144);
  gemm_bt<true><<<dim3(24, 64), 256, 0, stream>>>(inA, w1b, in_b, (void*)qkv,
                                                  8192, 3072, 1024);
  rope_kernel<<<8192, 256, 0, stream>>>(qkv, pos, Qg, Kg);
  vtrans_kernel<<<dim3(32, 64), 256, 0, stream>>>(qkv, Vt);
  attn_kernel<<<dim3(32, 64), 256, 0, stream>>>(Qg, Kg, Vt, attn, ctx);
  gemm_bt<false><<<dim3(8, 64), 256, 0, stream>>>(ctx, w2b, out_b, (void*)out,
                                                  8192, 1024, 1024);
}